// Round 5
// baseline (107.024 us; speedup 1.0000x reference)
//
#include <hip/hip_runtime.h>
#include <hip/hip_bf16.h>

using short8  = __attribute__((ext_vector_type(8))) short;   // 8 bf16 (4 VGPRs)
using floatx4 = __attribute__((ext_vector_type(4))) float;   // 4 fp32 acc

#define B_ROWS 4096
#define NTOT   8192
#define DD     128
#define NTILE  64                    // number of 128-row tiles
#define SQRTC1 1.6986436f            // sqrt(2*log2(e)) — inputs pre-scaled so MFMA yields C1*dot
#define E2f    7.389056098930650f    // exp(2): diagonal self-term to subtract
#define LN2f   0.6931471805599453f   // loss = -d'*ln2 + log(l - e^2)

// ---------------- kernel 1: L2-normalize rows, scale by sqrt(C1), cast bf16 ----------------
__global__ __launch_bounds__(256) void nrm_kernel(const float* __restrict__ zi,
                                                  const float* __restrict__ zj,
                                                  __hip_bfloat16* __restrict__ zb) {
    int tid  = threadIdx.x;
    int wave = tid >> 6, lane = tid & 63;
    int row  = blockIdx.x * 4 + wave;
    const float* src = (row < B_ROWS) ? (zi + (size_t)row * DD)
                                      : (zj + (size_t)(row - B_ROWS) * DD);
    float2 v = *(const float2*)(src + lane * 2);
    float s = v.x * v.x + v.y * v.y;
    #pragma unroll
    for (int m = 1; m <= 32; m <<= 1) s += __shfl_xor(s, m, 64);
    float scale = SQRTC1 / fmaxf(sqrtf(s), 1e-12f);
    __hip_bfloat16* dst = zb + (size_t)row * DD + lane * 2;
    dst[0] = __float2bfloat16(v.x * scale);
    dst[1] = __float2bfloat16(v.y * scale);
}

// ---------------- kernel 2: triangular fused sim-GEMM, fully-coalesced staging ----------------
// 2080 blocks = (bi<=bj) pairs of 128-row tiles. Block 256 thr = 4 waves, 32 A-rows/wave.
// BOTH tiles staged via coalesced loads (16 lanes read one contiguous 256B row) into
// xor-swizzled LDS (kc8 ^ row&15 — 2-way banks, free). A-frags read from LDS once.
// csum/rsum alias the A-tile region (dead after A-frag loads; barriers protect diag blocks).
// Positive-pair dots (tile diagonal of bj==bi+32 blocks) extracted from MFMA accs.
__global__ __launch_bounds__(256, 2) void sim_kernel(const __hip_bfloat16* __restrict__ zbf,
                                                     float* __restrict__ lp2,
                                                     float* __restrict__ pw) {
    __shared__ uint4 lds[4096];           // [0,2048): A tile, [2048,4096): B tile — 64 KB
    float* scratch = (float*)lds;         // aliases A region
    float* csum = scratch;                // [4][128] per-wave col partials (offdiag only)
    float* rsum = scratch + 512;          // [128] row partials

    const short* zs = (const short*)zbf;
    int tid = threadIdx.x;
    int w = tid >> 6, lane = tid & 63;
    int q = lane >> 4, n16 = lane & 15;

    // decode blockIdx.x -> (bi, bj), bi<=bj over NTILE=64
    int idx = blockIdx.x;
    int a = (int)((129.0f - sqrtf(16641.0f - 8.0f * (float)idx)) * 0.5f);
    while ((a + 1) * 64 - ((a + 1) * a) / 2 <= idx) ++a;
    while (a * 64 - (a * (a - 1)) / 2 > idx) --a;
    int bi = a, bj = a + (idx - (a * 64 - (a * (a - 1)) / 2));
    bool offdiag = (bi != bj);
    bool ispos   = (bj == bi + 32);       // these blocks hold the positive pairs on their diagonal

    // ---- stage tiles, coalesced: chunk c = tid + 256*rr; lanes 0-15 read a 256B row
    int nchunk = offdiag ? 4096 : 2048;   // diagonal block: stage A only, B aliases A
    #pragma unroll
    for (int rr = 0; rr < 16; ++rr) {
        if (rr * 256 < nchunk) {
            int c = tid + 256 * rr;
            int t = c >> 11, ct = c & 2047;
            int row = ct >> 4, kc8 = ct & 15;
            int grow = (t ? bj : bi) * 128 + row;
            lds[t * 2048 + row * 16 + (kc8 ^ (row & 15))] =
                *(const uint4*)(zs + (size_t)grow * DD + kc8 * 8);
        }
    }
    __syncthreads();

    // ---- A fragments from LDS: rows w*32+rs*16+n16; 16B chunk kc*4+q, xor-swizzled
    short8 af[2][4];
    #pragma unroll
    for (int rs = 0; rs < 2; ++rs) {
        int row = w * 32 + rs * 16 + n16;
        #pragma unroll
        for (int kc = 0; kc < 4; ++kc)
            af[rs][kc] = *(const short8*)&lds[row * 16 + ((kc * 4 + q) ^ n16)];
    }
    __syncthreads();   // A region now safe to reuse for csum (offdiag); diag keeps reading it as B

    const uint4* Bb = offdiag ? (lds + 2048) : lds;

    float rl[2][4];
    #pragma unroll
    for (int rs = 0; rs < 2; ++rs)
        #pragma unroll
        for (int r = 0; r < 4; ++r) rl[rs][r] = 0.f;

    #pragma unroll
    for (int st = 0; st < 8; ++st) {
        floatx4 acc[2] = {(floatx4){0.f,0.f,0.f,0.f}, (floatx4){0.f,0.f,0.f,0.f}};
        #pragma unroll
        for (int kc = 0; kc < 4; ++kc) {
            short8 bf = *(const short8*)&Bb[(st * 16 + n16) * 16 + ((kc * 4 + q) ^ n16)];
            acc[0] = __builtin_amdgcn_mfma_f32_16x16x32_bf16(af[0][kc], bf, acc[0], 0, 0, 0);
            acc[1] = __builtin_amdgcn_mfma_f32_16x16x32_bf16(af[1][kc], bf, acc[1], 0, 0, 0);
        }
        float e[2][4];
        #pragma unroll
        for (int rs = 0; rs < 2; ++rs)
            #pragma unroll
            for (int r = 0; r < 4; ++r) {
                e[rs][r] = __builtin_amdgcn_exp2f(acc[rs][r]);
                rl[rs][r] += e[rs][r];
                // positive-pair extraction: tile-diagonal of bj==bi+32 blocks
                if (ispos && st == w * 2 + rs && n16 == q * 4 + r) {
                    int m = w * 32 + rs * 16 + n16;
                    pw[bi * 128 + m] = acc[rs][r];
                    pw[bj * 128 + m] = acc[rs][r];
                }
            }
        if (offdiag) {
            float cp = ((e[0][0] + e[0][1]) + (e[0][2] + e[0][3]))
                     + ((e[1][0] + e[1][1]) + (e[1][2] + e[1][3]));
            cp += __shfl_xor(cp, 16, 64);
            cp += __shfl_xor(cp, 32, 64);
            if (q == 0) csum[w * 128 + st * 16 + n16] = cp;
        }
    }

    // row sums: reduce over 16 col-lanes in-register
    float vred[2][4];
    #pragma unroll
    for (int rs = 0; rs < 2; ++rs)
        #pragma unroll
        for (int r = 0; r < 4; ++r) {
            float v = rl[rs][r];
            v += __shfl_xor(v, 1, 64);
            v += __shfl_xor(v, 2, 64);
            v += __shfl_xor(v, 4, 64);
            v += __shfl_xor(v, 8, 64);
            vred[rs][r] = v;
        }
    __syncthreads();   // all tile reads done (protects diag blocks' B==A region)
    if (n16 == 0) {
        #pragma unroll
        for (int rs = 0; rs < 2; ++rs)
            #pragma unroll
            for (int r = 0; r < 4; ++r)
                rsum[w * 32 + rs * 16 + q * 4 + r] = vred[rs][r];
    }
    __syncthreads();
    if (tid < 128) {
        lp2[(size_t)bj * NTOT + bi * 128 + tid] = rsum[tid];
        if (offdiag)
            lp2[(size_t)bi * NTOT + bj * 128 + tid] =
                (csum[tid] + csum[128 + tid]) + (csum[256 + tid] + csum[384 + tid]);
    }
}

// ---------------- kernel 3: finalize ----------------
// loss_i = -d'*ln2 + ln(sum_exp2 - e^2); mean via block reduce + 32 atomics
__global__ __launch_bounds__(256) void fin_kernel(const float* __restrict__ lp2,
                                                  const float* __restrict__ pw,
                                                  float* __restrict__ out) {
    __shared__ float red[256];
    int row = blockIdx.x * 256 + threadIdx.x;

    float l = 0.f;
    #pragma unroll
    for (int s = 0; s < 64; ++s) l += lp2[(size_t)s * NTOT + row];   // coalesced (lane==row)

    float loss = -pw[row] * LN2f + logf(l - E2f);
    red[threadIdx.x] = loss;
    __syncthreads();
    #pragma unroll
    for (int s = 128; s > 0; s >>= 1) {
        if (threadIdx.x < s) red[threadIdx.x] += red[threadIdx.x + s];
        __syncthreads();
    }
    if (threadIdx.x == 0) atomicAdd(out, red[0] * (1.0f / (float)NTOT));
}

extern "C" void kernel_launch(void* const* d_in, const int* in_sizes, int n_in,
                              void* d_out, int out_size, void* d_ws, size_t ws_size,
                              hipStream_t stream) {
    const float* zi = (const float*)d_in[0];
    const float* zj = (const float*)d_in[1];
    float* out = (float*)d_out;

    __hip_bfloat16* zb = (__hip_bfloat16*)d_ws;                     // 2 MB
    float* lp2 = (float*)((char*)d_ws + (size_t)NTOT * DD * 2);     // 2 MB  [64][8192]
    float* pw  = lp2 + (size_t)NTILE * NTOT;                        // 32 KB [8192]

    hipMemsetAsync(d_out, 0, sizeof(float), stream);
    nrm_kernel<<<NTOT / 4, 256, 0, stream>>>(zi, zj, zb);
    sim_kernel<<<2080, 256, 0, stream>>>(zb, lp2, pw);
    fin_kernel<<<NTOT / 256, 256, 0, stream>>>(lp2, pw, out);
}

// Round 6
// 100.550 us; speedup vs baseline: 1.0644x; 1.0644x over previous
//
#include <hip/hip_runtime.h>
#include <hip/hip_bf16.h>

using short8  = __attribute__((ext_vector_type(8))) short;   // 8 bf16 (4 VGPRs)
using floatx4 = __attribute__((ext_vector_type(4))) float;   // 4 fp32 acc

#define B_ROWS 4096
#define NTOT   8192
#define DD     128
#define NTILE  64                    // 128-row tiles
#define TCHUNK 2048                  // 16B chunks per tile (128 rows x 16 kc8)
#define TSHORT 16384                 // shorts per tile
#define SQRTC1 1.6986436f            // sqrt(2*log2(e)) — inputs pre-scaled: MFMA yields C1*dot
#define E2f    7.389056098930650f    // exp(2): diagonal self-term
#define LN2f   0.6931471805599453f   // loss = -d'*ln2 + log(l - e^2)

// async global->LDS DMA, 16B/lane; LDS dest is wave-uniform base + lane*16
#define GLOAD_LDS16(gptr, lptr)                                                          \
    __builtin_amdgcn_global_load_lds((const __attribute__((address_space(1))) void*)(gptr), \
                                     (__attribute__((address_space(3))) void*)(lptr), 16, 0, 0)

// -------- kernel 1: normalize + scale + cast, emit k-major tile layout --------
// zb chunk layout: [tile(64)][kc8(16)][row(128)], chunk = 8 shorts = 16 B.
// One block per 128-row tile. Also zeroes d_out (replaces memset launch).
__global__ __launch_bounds__(256) void nrm_kernel(const float* __restrict__ zi,
                                                  const float* __restrict__ zj,
                                                  __hip_bfloat16* __restrict__ zb,
                                                  float* __restrict__ out) {
    __shared__ float sc[128];
    int T = blockIdx.x;
    const float* src = (T < 32) ? (zi + (size_t)T * 128 * DD)
                                : (zj + (size_t)(T - 32) * 128 * DD);
    int t = threadIdx.x;
    if (T == 0 && t == 0) out[0] = 0.f;

    // norms: thread t covers half-row (64 floats); pair-combine via shuffle
    {
        int row = t >> 1, half = t & 1;
        const float4* p = (const float4*)(src + (size_t)row * DD + half * 64);
        float s = 0.f;
        #pragma unroll
        for (int i = 0; i < 16; ++i) {
            float4 v = p[i];
            s += (v.x * v.x + v.y * v.y) + (v.z * v.z + v.w * v.w);
        }
        s += __shfl_xor(s, 1, 64);
        if (half == 0) sc[row] = SQRTC1 / fmaxf(sqrtf(s), 1e-12f);
    }
    __syncthreads();

    // write k-major chunks, coalesced: chunk c = t + 256*rr -> (kc8 = c>>7, row = c&127)
    short* dst = (short*)zb + (size_t)T * TSHORT;
    #pragma unroll
    for (int rr = 0; rr < 8; ++rr) {
        int c = t + 256 * rr, row = c & 127, kc8 = c >> 7;
        const float4* p = (const float4*)(src + (size_t)row * DD + kc8 * 8);
        float4 v0 = p[0], v1 = p[1];
        float s = sc[row];
        __hip_bfloat16 h[8];
        h[0] = __float2bfloat16(v0.x * s); h[1] = __float2bfloat16(v0.y * s);
        h[2] = __float2bfloat16(v0.z * s); h[3] = __float2bfloat16(v0.w * s);
        h[4] = __float2bfloat16(v1.x * s); h[5] = __float2bfloat16(v1.y * s);
        h[6] = __float2bfloat16(v1.z * s); h[7] = __float2bfloat16(v1.w * s);
        *(short8*)(dst + (size_t)c * 8) = *(const short8*)h;
    }
}

// -------- kernel 2: triangular fused sim-GEMM, k-major tiles --------
// 2080 blocks = (bi<=bj) tile pairs. 4 waves x 32 A-rows. B tile DMA'd coalesced
// (layout already k-major -> verbatim copy, conflict-free fragment reads).
// A-fragments straight from global (4x256B segments/load). One barrier pre-loop.
__global__ __launch_bounds__(256, 4) void sim_kernel(const __hip_bfloat16* __restrict__ zbf,
                                                     float* __restrict__ lp2,
                                                     float* __restrict__ pw) {
    __shared__ uint4 ldsB[TCHUNK];    // 32 KB, [kc8(16)][row(128)]
    __shared__ float csum[512];       // [wave][128] col partials (offdiag)
    __shared__ float rsum[128];

    const short* zs = (const short*)zbf;
    int tid = threadIdx.x;
    int w = tid >> 6, lane = tid & 63;
    int q = lane >> 4, n16 = lane & 15;

    // decode blockIdx.x -> (bi <= bj)
    int idx = blockIdx.x;
    int a = (int)((129.0f - sqrtf(16641.0f - 8.0f * (float)idx)) * 0.5f);
    while ((a + 1) * 64 - ((a + 1) * a) / 2 <= idx) ++a;
    while (a * 64 - (a * (a - 1)) / 2 > idx) --a;
    int bi = a, bj = a + (idx - (a * 64 - (a * (a - 1)) / 2));
    bool offdiag = (bi != bj);
    bool ispos   = (bj == bi + 32);

    // stage B tile: fully coalesced DMA, verbatim k-major copy
    const short* gB = zs + (size_t)bj * TSHORT;
    #pragma unroll
    for (int rr = 0; rr < 8; ++rr)
        GLOAD_LDS16(gB + (size_t)(tid + 256 * rr) * 8, &ldsB[tid + 256 * rr]);

    // A fragments direct from global: chunk (kc*4+q)*128 + local_row
    const short* gA = zs + (size_t)bi * TSHORT;
    short8 af[2][4];
    #pragma unroll
    for (int rs = 0; rs < 2; ++rs) {
        int lr = w * 32 + rs * 16 + n16;
        #pragma unroll
        for (int kc = 0; kc < 4; ++kc)
            af[rs][kc] = *(const short8*)(gA + (size_t)((kc * 4 + q) * 128 + lr) * 8);
    }
    __syncthreads();   // drains DMA (vmcnt) before fragment reads

    float rl[2][4];
    #pragma unroll
    for (int rs = 0; rs < 2; ++rs)
        #pragma unroll
        for (int r = 0; r < 4; ++r) rl[rs][r] = 0.f;

    #pragma unroll
    for (int st = 0; st < 8; ++st) {
        floatx4 acc[2] = {(floatx4){0.f,0.f,0.f,0.f}, (floatx4){0.f,0.f,0.f,0.f}};
        #pragma unroll
        for (int kc = 0; kc < 4; ++kc) {
            short8 bf = *(const short8*)&ldsB[(kc * 4 + q) * 128 + st * 16 + n16];
            acc[0] = __builtin_amdgcn_mfma_f32_16x16x32_bf16(af[0][kc], bf, acc[0], 0, 0, 0);
            acc[1] = __builtin_amdgcn_mfma_f32_16x16x32_bf16(af[1][kc], bf, acc[1], 0, 0, 0);
        }
        float e[2][4];
        #pragma unroll
        for (int rs = 0; rs < 2; ++rs)
            #pragma unroll
            for (int r = 0; r < 4; ++r) {
                e[rs][r] = __builtin_amdgcn_exp2f(acc[rs][r]);
                rl[rs][r] += e[rs][r];
                // positive pairs live on the tile diagonal of bj==bi+32 blocks
                if (ispos && st == w * 2 + rs && n16 == q * 4 + r) {
                    int m = w * 32 + rs * 16 + n16;
                    pw[bi * 128 + m] = acc[rs][r];
                    pw[bj * 128 + m] = acc[rs][r];
                }
            }
        if (offdiag) {  // col-sum credit (symmetry): sum this wave's 32 rows
            float cp = ((e[0][0] + e[0][1]) + (e[0][2] + e[0][3]))
                     + ((e[1][0] + e[1][1]) + (e[1][2] + e[1][3]));
            cp += __shfl_xor(cp, 16, 64);
            cp += __shfl_xor(cp, 32, 64);
            if (q == 0) csum[w * 128 + st * 16 + n16] = cp;
        }
    }

    // row sums: reduce across the 16 col-lanes
    float vred[2][4];
    #pragma unroll
    for (int rs = 0; rs < 2; ++rs)
        #pragma unroll
        for (int r = 0; r < 4; ++r) {
            float v = rl[rs][r];
            v += __shfl_xor(v, 1, 64);
            v += __shfl_xor(v, 2, 64);
            v += __shfl_xor(v, 4, 64);
            v += __shfl_xor(v, 8, 64);
            vred[rs][r] = v;
        }
    if (n16 == 0) {
        #pragma unroll
        for (int rs = 0; rs < 2; ++rs)
            #pragma unroll
            for (int r = 0; r < 4; ++r)
                rsum[w * 32 + rs * 16 + q * 4 + r] = vred[rs][r];
    }
    __syncthreads();
    if (tid < 128) {
        lp2[(size_t)bj * NTOT + bi * 128 + tid] = rsum[tid];
        if (offdiag)
            lp2[(size_t)bi * NTOT + bj * 128 + tid] =
                (csum[tid] + csum[128 + tid]) + (csum[256 + tid] + csum[384 + tid]);
    }
}

// -------- kernel 3: finalize --------
__global__ __launch_bounds__(256) void fin_kernel(const float* __restrict__ lp2,
                                                  const float* __restrict__ pw,
                                                  float* __restrict__ out) {
    __shared__ float red[256];
    int row = blockIdx.x * 256 + threadIdx.x;

    float l = 0.f;
    #pragma unroll
    for (int s = 0; s < 64; ++s) l += lp2[(size_t)s * NTOT + row];   // coalesced

    float loss = -pw[row] * LN2f + logf(l - E2f);
    red[threadIdx.x] = loss;
    __syncthreads();
    #pragma unroll
    for (int s = 128; s > 0; s >>= 1) {
        if (threadIdx.x < s) red[threadIdx.x] += red[threadIdx.x + s];
        __syncthreads();
    }
    if (threadIdx.x == 0) atomicAdd(out, red[0] * (1.0f / (float)NTOT));
}

extern "C" void kernel_launch(void* const* d_in, const int* in_sizes, int n_in,
                              void* d_out, int out_size, void* d_ws, size_t ws_size,
                              hipStream_t stream) {
    const float* zi = (const float*)d_in[0];
    const float* zj = (const float*)d_in[1];
    float* out = (float*)d_out;

    __hip_bfloat16* zb = (__hip_bfloat16*)d_ws;                     // 2 MB (k-major tiles)
    float* lp2 = (float*)((char*)d_ws + (size_t)NTOT * DD * 2);     // 2 MB  [64][8192]
    float* pw  = lp2 + (size_t)NTILE * NTOT;                        // 32 KB [8192]

    nrm_kernel<<<NTILE, 256, 0, stream>>>(zi, zj, zb, out);         // also zeroes out
    sim_kernel<<<2080, 256, 0, stream>>>(zb, lp2, pw);
    fin_kernel<<<NTOT / 256, 256, 0, stream>>>(lp2, pw, out);
}